// Round 3
// baseline (515.374 us; speedup 1.0000x reference)
//
#include <hip/hip_runtime.h>
#include <stdint.h>

// Problem constants (from reference): B=128, T=80, C=6625, D=96
constexpr int BB = 128;
constexpr int TT = 80;
constexpr int CC = 6625;
constexpr int DD = 96;
constexpr int NN = BB * TT;   // 10240 rows
constexpr int NSLOT = 8;      // accumulator slots to spread same-address atomics

typedef float f32x4 __attribute__((ext_vector_type(4)));

// One block per row: argmax of logits[row][0..C) (first-index tie-break),
// then squared distance feats[row] vs centers[label], clipped.
// Cross-block combine is atomics-only (device scope): no plain-load
// visibility assumptions across XCDs. The last block to finish (completion
// counter) reads the slots back via atomicAdd(+0.0) and writes the result.
__global__ __launch_bounds__(256) void centerloss_fused_kernel(
    const float* __restrict__ logits,
    const float* __restrict__ feats,
    const float* __restrict__ centers,
    double* __restrict__ acc,          // [NSLOT] zeroed by memset
    unsigned int* __restrict__ counter, // zeroed by memset
    float* __restrict__ out)
{
    const int row = blockIdx.x;
    const int tid = threadIdx.x;
    const float* __restrict__ lrow = logits + (size_t)row * CC;

    // ---------- per-thread argmax scan (increasing index order) ----------
    float bestv = -__builtin_inff();
    int   besti = 0x7fffffff;

    // peel to 16B alignment (row byte offset is only 4B aligned: 26500 % 16 = 4)
    const int mis = (int)(((uintptr_t)lrow >> 2) & 3);  // misalignment in floats
    const int k = (4 - mis) & 3;
    if (tid < k) {
        bestv = lrow[tid];
        besti = tid;
    }

    const int nvec = (CC - k) >> 2;           // 1655 or 1656
    const f32x4* __restrict__ lv = (const f32x4*)(lrow + k);

    // Fixed 7-deep batch: issue ALL loads before any compare (7*256=1792>=nvec).
    // Out-of-range lanes clamp to nvec-1 (harmless duplicate load), compares
    // are predicated on validity.
    f32x4 v[7];
    #pragma unroll
    for (int it = 0; it < 7; ++it) {
        int j  = tid + it * 256;
        int jc = j < nvec ? j : (nvec - 1);
        v[it] = __builtin_nontemporal_load(&lv[jc]);
    }
    #pragma unroll
    for (int it = 0; it < 7; ++it) {
        int j = tid + it * 256;
        if (j < nvec) {
            const int base = k + 4 * j;
            f32x4 t = v[it];
            if (t.x > bestv) { bestv = t.x; besti = base;     }
            if (t.y > bestv) { bestv = t.y; besti = base + 1; }
            if (t.z > bestv) { bestv = t.z; besti = base + 2; }
            if (t.w > bestv) { bestv = t.w; besti = base + 3; }
        }
    }

    const int tail_start = k + 4 * nvec;
    const int tail_n = CC - tail_start;  // 0..3; tail indices > all scanned ones
    if (tid < tail_n) {
        float val = lrow[tail_start + tid];
        if (val > bestv) { bestv = val; besti = tail_start + tid; }
    }

    // ---------- wave (64-lane) butterfly reduce with first-index tie-break ----
    #pragma unroll
    for (int off = 32; off > 0; off >>= 1) {
        float ov = __shfl_xor(bestv, off);
        int   oi = __shfl_xor(besti, off);
        if (ov > bestv || (ov == bestv && oi < besti)) { bestv = ov; besti = oi; }
    }

    __shared__ float s_wv[4];
    __shared__ int   s_wi[4];
    __shared__ int   s_label;
    __shared__ double s_wd[4];

    const int wave = tid >> 6;
    if ((tid & 63) == 0) { s_wv[wave] = bestv; s_wi[wave] = besti; }
    __syncthreads();
    if (tid == 0) {
        float bv = s_wv[0]; int bi = s_wi[0];
        #pragma unroll
        for (int w = 1; w < 4; ++w) {
            float ov = s_wv[w]; int oi = s_wi[w];
            if (ov > bv || (ov == bv && oi < bi)) { bv = ov; bi = oi; }
        }
        s_label = bi;
    }
    __syncthreads();
    const int lab = s_label;

    // ---------- squared distance to labeled center (f64 accumulate) ----------
    double d2 = 0.0;
    if (tid < DD) {
        float df = feats[(size_t)row * DD + tid] - centers[(size_t)lab * DD + tid];
        d2 = (double)df * (double)df;
    }
    #pragma unroll
    for (int off = 32; off > 0; off >>= 1) d2 += __shfl_xor(d2, off);
    if ((tid & 63) == 0) s_wd[wave] = d2;
    __syncthreads();

    if (tid == 0) {
        double s = s_wd[0] + s_wd[1] + s_wd[2] + s_wd[3];
        // clip(dist, 1e-12, 1e12) exactly as reference applies per-entry
        s = s < 1e-12 ? 1e-12 : (s > 1e12 ? 1e12 : s);

        // device-scope f64 atomic add into one of NSLOT slots
        atomicAdd(&acc[row & (NSLOT - 1)], s);
        __threadfence();  // release: slot add visible before counter bump
        unsigned int prev = atomicAdd(counter, 1u);
        if (prev == (unsigned int)(NN - 1)) {
            // last block: all slot adds happened-before (release-fenced).
            // Read slots coherently via atomic read-modify-write of +0.0.
            double tot = 0.0;
            #pragma unroll
            for (int i = 0; i < NSLOT; ++i) tot += atomicAdd(&acc[i], 0.0);
            // off-label entries: each of the (C-1) zeroed entries per row
            // clips to 1e-12 -> adds (C-1)*1e-12 to the mean.
            out[0] = (float)(tot / (double)NN + (double)(CC - 1) * 1e-12);
        }
    }
}

extern "C" void kernel_launch(void* const* d_in, const int* in_sizes, int n_in,
                              void* d_out, int out_size, void* d_ws, size_t ws_size,
                              hipStream_t stream) {
    const float* logits  = (const float*)d_in[0];  // [B,T,C] f32
    const float* feats   = (const float*)d_in[1];  // [B,T,D] f32
    const float* centers = (const float*)d_in[2];  // [C,D]   f32
    float* out = (float*)d_out;

    double* acc = (double*)d_ws;                          // NSLOT doubles
    unsigned int* counter = (unsigned int*)((char*)d_ws + NSLOT * sizeof(double));

    // zero accumulators + counter each call (graph-capturable async memset)
    hipMemsetAsync(d_ws, 0, NSLOT * sizeof(double) + sizeof(unsigned int), stream);

    centerloss_fused_kernel<<<NN, 256, 0, stream>>>(logits, feats, centers,
                                                    acc, counter, out);
}

// Round 4
// 48.309 us; speedup vs baseline: 10.6683x; 10.6683x over previous
//
#include <hip/hip_runtime.h>
#include <stdint.h>

// Problem constants (from reference): B=128, T=80, C=6625, D=96
constexpr int BB = 128;
constexpr int TT = 80;
constexpr int CC = 6625;
constexpr int DD = 96;
constexpr int NN = BB * TT;   // 10240 rows

typedef float f32x4 __attribute__((ext_vector_type(4)));

// One block per row: argmax of logits[row][0..C) (first-index tie-break),
// then squared distance feats[row] vs centers[label], clipped, -> partial[row].
// Cross-kernel visibility comes from the kernel boundary (no fences needed).
__global__ __launch_bounds__(256) void centerloss_row_kernel(
    const float* __restrict__ logits,
    const float* __restrict__ feats,
    const float* __restrict__ centers,
    float* __restrict__ partial)
{
    const int row = blockIdx.x;
    const int tid = threadIdx.x;
    const float* __restrict__ lrow = logits + (size_t)row * CC;

    // ---------- per-thread argmax scan (increasing index order) ----------
    float bestv = -__builtin_inff();
    int   besti = 0x7fffffff;

    // peel to 16B alignment (row byte offset is only 4B aligned: 26500 % 16 = 4)
    const int mis = (int)(((uintptr_t)lrow >> 2) & 3);  // misalignment in floats
    const int k = (4 - mis) & 3;
    if (tid < k) {
        bestv = lrow[tid];
        besti = tid;
    }

    const int nvec = (CC - k) >> 2;           // 1655 or 1656
    const f32x4* __restrict__ lv = (const f32x4*)(lrow + k);

    // Fixed 7-deep batch: issue ALL loads before any compare (7*256=1792>=nvec).
    // Out-of-range lanes clamp to nvec-1 (harmless duplicate load), compares
    // are predicated on validity.
    f32x4 v[7];
    #pragma unroll
    for (int it = 0; it < 7; ++it) {
        int j  = tid + it * 256;
        int jc = j < nvec ? j : (nvec - 1);
        v[it] = __builtin_nontemporal_load(&lv[jc]);
    }
    #pragma unroll
    for (int it = 0; it < 7; ++it) {
        int j = tid + it * 256;
        if (j < nvec) {
            const int base = k + 4 * j;
            f32x4 t = v[it];
            if (t.x > bestv) { bestv = t.x; besti = base;     }
            if (t.y > bestv) { bestv = t.y; besti = base + 1; }
            if (t.z > bestv) { bestv = t.z; besti = base + 2; }
            if (t.w > bestv) { bestv = t.w; besti = base + 3; }
        }
    }

    const int tail_start = k + 4 * nvec;
    const int tail_n = CC - tail_start;  // 0..3; tail indices > all scanned ones
    if (tid < tail_n) {
        float val = lrow[tail_start + tid];
        if (val > bestv) { bestv = val; besti = tail_start + tid; }
    }

    // ---------- wave (64-lane) butterfly reduce with first-index tie-break ----
    #pragma unroll
    for (int off = 32; off > 0; off >>= 1) {
        float ov = __shfl_xor(bestv, off);
        int   oi = __shfl_xor(besti, off);
        if (ov > bestv || (ov == bestv && oi < besti)) { bestv = ov; besti = oi; }
    }

    __shared__ float s_wv[4];
    __shared__ int   s_wi[4];
    __shared__ int   s_label;
    __shared__ double s_wd[4];

    const int wave = tid >> 6;
    if ((tid & 63) == 0) { s_wv[wave] = bestv; s_wi[wave] = besti; }
    __syncthreads();
    if (tid == 0) {
        float bv = s_wv[0]; int bi = s_wi[0];
        #pragma unroll
        for (int w = 1; w < 4; ++w) {
            float ov = s_wv[w]; int oi = s_wi[w];
            if (ov > bv || (ov == bv && oi < bi)) { bv = ov; bi = oi; }
        }
        s_label = bi;
    }
    __syncthreads();
    const int lab = s_label;

    // ---------- squared distance to labeled center (f64 accumulate) ----------
    double d2 = 0.0;
    if (tid < DD) {
        float df = feats[(size_t)row * DD + tid] - centers[(size_t)lab * DD + tid];
        d2 = (double)df * (double)df;
    }
    #pragma unroll
    for (int off = 32; off > 0; off >>= 1) d2 += __shfl_xor(d2, off);
    if ((tid & 63) == 0) s_wd[wave] = d2;
    __syncthreads();
    if (tid == 0) {
        double s = s_wd[0] + s_wd[1] + s_wd[2] + s_wd[3];
        // clip(dist, 1e-12, 1e12) exactly as reference applies per-entry
        s = s < 1e-12 ? 1e-12 : (s > 1e12 ? 1e12 : s);
        // f32 partial: value ~O(200), rounding ~1e-5/row; total error ~1e-3
        // vs 3.84 harness threshold.
        partial[row] = (float)s;
    }
}

__global__ __launch_bounds__(1024) void centerloss_reduce_kernel(
    const float* __restrict__ partial, float* __restrict__ out)
{
    const int tid = threadIdx.x;
    // issue all 10 loads before the dependent add chain
    float v[NN / 1024];
    #pragma unroll
    for (int it = 0; it < NN / 1024; ++it) v[it] = partial[tid + it * 1024];
    double s = 0.0;
    #pragma unroll
    for (int it = 0; it < NN / 1024; ++it) s += (double)v[it];
    #pragma unroll
    for (int off = 32; off > 0; off >>= 1) s += __shfl_xor(s, off);
    __shared__ double ws[16];
    const int wave = tid >> 6;
    if ((tid & 63) == 0) ws[wave] = s;
    __syncthreads();
    if (tid == 0) {
        double tot = 0.0;
        #pragma unroll
        for (int w = 0; w < 16; ++w) tot += ws[w];
        // off-label entries: each of the (C-1) zeroed entries per row clips
        // to 1e-12 -> adds (C-1)*1e-12 to the mean.
        out[0] = (float)(tot / (double)NN + (double)(CC - 1) * 1e-12);
    }
}

extern "C" void kernel_launch(void* const* d_in, const int* in_sizes, int n_in,
                              void* d_out, int out_size, void* d_ws, size_t ws_size,
                              hipStream_t stream) {
    const float* logits  = (const float*)d_in[0];  // [B,T,C] f32
    const float* feats   = (const float*)d_in[1];  // [B,T,D] f32
    const float* centers = (const float*)d_in[2];  // [C,D]   f32
    float* out = (float*)d_out;
    float* partial = (float*)d_ws;                 // NN floats = 40 KB

    centerloss_row_kernel<<<NN, 256, 0, stream>>>(logits, feats, centers, partial);
    centerloss_reduce_kernel<<<1, 1024, 0, stream>>>(partial, out);
}